// Round 9
// baseline (1679.984 us; speedup 1.0000x reference)
//
#include <hip/hip_runtime.h>
#include <math.h>

// ---------------- problem constants ----------------
#define BB     64
#define LLEN   197
#define BLROWS 12608      // BB*LLEN
#define MPAD   12672      // BLROWS padded to 99*128
#define DMODEL 192
#define NHEAD  3
#define DHEAD  64
#define M2FEAT 256
#define FFDIM  768
#define NDEPTH 12
#define NCLS   1000
#define NPATCH 196
#define BPROWS 12544      // BB*NPATCH (= 98*128 exactly)
#define KPATCH 768
#define PHIRS  264        // Phi LDS row stride (256 + 8 pad, 16B-aligned)

#define MODE_PLAIN 0
#define MODE_RELU  1

typedef unsigned short ushort;
typedef __attribute__((ext_vector_type(8))) short bf16x8;
typedef __attribute__((ext_vector_type(4))) float floatx4;
typedef __attribute__((ext_vector_type(4))) short short4v;

__device__ __forceinline__ float wave_reduce_sum(float v) {
#pragma unroll
  for (int s = 32; s > 0; s >>= 1) v += __shfl_xor(v, s, 64);
  return v;
}
__device__ __forceinline__ ushort f2bf(float f) {  // RNE fp32->bf16
  unsigned u = __float_as_uint(f);
  return (ushort)((u + 0x7fffu + ((u >> 16) & 1u)) >> 16);
}
__device__ __forceinline__ float bf2f(ushort u) {
  return __uint_as_float(((unsigned)u) << 16);
}
// async global->LDS, 16 B per lane; LDS dest wave-uniform (HW adds lane*16)
__device__ __forceinline__ void gll16(const ushort* g, ushort* l) {
  __builtin_amdgcn_global_load_lds(
      (const __attribute__((address_space(1))) void*)g,
      (__attribute__((address_space(3))) void*)l, 16, 0, 0);
}

// =========== bf16 GEMM, 128x64 tile, dbuf LDS (wide-N GEMMs) ===========
// block 256 = 4 waves (2x2 of 64x32). bf16 out with bias (+relu).
__global__ __launch_bounds__(256) void gemm_bf2(
    const ushort* __restrict__ A, int lda,
    const ushort* __restrict__ W, int ldw,
    const float* __restrict__ bias,
    ushort* __restrict__ C, int ldc, int Kdim, int mode)
{
  __shared__ __align__(16) ushort As[2][128 * 32];   // 16 KB
  __shared__ __align__(16) ushort Ws[2][64 * 32];    // 8 KB
  const int tid = threadIdx.x;
  const int bm = blockIdx.x, bn = blockIdx.y;
  const int wave = tid >> 6, lane = tid & 63;
  const int wm = (wave >> 1) * 64, wn = (wave & 1) * 32;
  const int quad = lane >> 4, l16 = lane & 15;
  const int lrow = lane >> 2, lk = (lane & 3) * 8;
  const ushort* Ap = A + (size_t)(bm * 128) * lda;
  const ushort* Wp = W + (size_t)(bn * 64) * ldw;
  floatx4 acc[4][2] = {};
  const int nT = Kdim >> 5;
#pragma unroll
  for (int t = 0; t < 2; ++t) {
    const int rb = (t * 4 + wave) * 16;
    gll16(Ap + (size_t)(rb + lrow) * lda + lk, &As[0][rb * 32]);
  }
  gll16(Wp + (size_t)(wave * 16 + lrow) * ldw + lk, &Ws[0][wave * 16 * 32]);
  for (int kt = 0; kt < nT; ++kt) {
    const int cur = kt & 1;
    __syncthreads();                 // drains prefetch(kt) (vmcnt0) + buf reuse
    if (kt + 1 < nT) {
      const int kk = (kt + 1) * 32, nxt = cur ^ 1;
#pragma unroll
      for (int t = 0; t < 2; ++t) {
        const int rb = (t * 4 + wave) * 16;
        gll16(Ap + (size_t)(rb + lrow) * lda + kk + lk, &As[nxt][rb * 32]);
      }
      gll16(Wp + (size_t)(wave * 16 + lrow) * ldw + kk + lk, &Ws[nxt][wave * 16 * 32]);
    }
    bf16x8 af[4], bf[2];
#pragma unroll
    for (int i = 0; i < 4; ++i)
      af[i] = *(const bf16x8*)&As[cur][(wm + i * 16 + l16) * 32 + quad * 8];
#pragma unroll
    for (int j = 0; j < 2; ++j)
      bf[j] = *(const bf16x8*)&Ws[cur][(wn + j * 16 + l16) * 32 + quad * 8];
#pragma unroll
    for (int i = 0; i < 4; ++i)
#pragma unroll
      for (int j = 0; j < 2; ++j)
        acc[i][j] = __builtin_amdgcn_mfma_f32_16x16x32_bf16(af[i], bf[j], acc[i][j], 0, 0, 0);
  }
#pragma unroll
  for (int j = 0; j < 2; ++j) {
    const int col = bn * 64 + wn + j * 16 + l16;
    const float bv = bias[col];
#pragma unroll
    for (int i = 0; i < 4; ++i)
#pragma unroll
      for (int r = 0; r < 4; ++r) {
        const int grow = bm * 128 + wm + i * 16 + quad * 4 + r;
        float o = acc[i][j][r] + bv;
        if (mode == MODE_RELU) o = fmaxf(o, 0.f);
        C[(size_t)grow * ldc + col] = f2bf(o);
      }
  }
}

// =========== bf16 GEMM, 128x32 tile (N=192 GEMMs: 6 N-tiles -> 594 blocks) ====
// block 256 = 4 waves (2x2 of 64x16). Direct bf16 out with bias, no split-K.
__global__ __launch_bounds__(256) void gemm_n32(
    const ushort* __restrict__ A, int lda,
    const ushort* __restrict__ W, int ldw,
    const float* __restrict__ bias,
    ushort* __restrict__ C, int ldc, int Kdim)
{
  __shared__ __align__(16) ushort As[2][128 * 32];   // 16 KB
  __shared__ __align__(16) ushort Ws[2][32 * 32];    // 4 KB
  const int tid = threadIdx.x;
  const int bm = blockIdx.x, bn = blockIdx.y;
  const int wave = tid >> 6, lane = tid & 63;
  const int wm = (wave >> 1) * 64, wn = (wave & 1) * 16;
  const int quad = lane >> 4, l16 = lane & 15;
  const int lrow = lane >> 2, lk = (lane & 3) * 8;
  const ushort* Ap = A + (size_t)(bm * 128) * lda;
  const ushort* Wp = W + (size_t)(bn * 32) * ldw;
  floatx4 acc[4] = {};
  const int nT = Kdim >> 5;
#pragma unroll
  for (int t = 0; t < 2; ++t) {
    const int rb = (t * 4 + wave) * 16;
    gll16(Ap + (size_t)(rb + lrow) * lda + lk, &As[0][rb * 32]);
  }
  if (wave < 2) gll16(Wp + (size_t)(wave * 16 + lrow) * ldw + lk, &Ws[0][wave * 16 * 32]);
  for (int kt = 0; kt < nT; ++kt) {
    const int cur = kt & 1;
    __syncthreads();
    if (kt + 1 < nT) {
      const int kk = (kt + 1) * 32, nxt = cur ^ 1;
#pragma unroll
      for (int t = 0; t < 2; ++t) {
        const int rb = (t * 4 + wave) * 16;
        gll16(Ap + (size_t)(rb + lrow) * lda + kk + lk, &As[nxt][rb * 32]);
      }
      if (wave < 2) gll16(Wp + (size_t)(wave * 16 + lrow) * ldw + kk + lk, &Ws[nxt][wave * 16 * 32]);
    }
    bf16x8 af[4], bf;
#pragma unroll
    for (int i = 0; i < 4; ++i)
      af[i] = *(const bf16x8*)&As[cur][(wm + i * 16 + l16) * 32 + quad * 8];
    bf = *(const bf16x8*)&Ws[cur][(wn + l16) * 32 + quad * 8];
#pragma unroll
    for (int i = 0; i < 4; ++i)
      acc[i] = __builtin_amdgcn_mfma_f32_16x16x32_bf16(af[i], bf, acc[i], 0, 0, 0);
  }
  const int col = bn * 32 + wn + l16;
  const float bv = bias[col];
#pragma unroll
  for (int i = 0; i < 4; ++i)
#pragma unroll
    for (int r = 0; r < 4; ++r) {
      const int grow = bm * 128 + wm + i * 16 + quad * 4 + r;
      C[(size_t)grow * ldc + col] = f2bf(acc[i][r] + bv);
    }
}

// =========== fused FAVOR-K + V-transpose + KV accumulation ===========
// grid (192 bh, 2 mh). Per 32-token chunk: u = K*scale @ Om_half^T (MFMA),
// phi = exp(+-u - off) -> LDS transposed [128 prow][32 l]; V transposed in LDS;
// KV[prow][d] += phiT @ VtT via MFMA. Out KVt [bh][80 d][256 f] (d=64 row: ksum).
__global__ __launch_bounds__(256) void kv_fused(
    const ushort* __restrict__ qkv, const ushort* __restrict__ OmT,
    ushort* __restrict__ KVt)
{
  __shared__ __align__(16) ushort Ks[32 * 64];    // 4 KB
  __shared__ __align__(16) ushort Vs[32 * 64];    // 4 KB
  __shared__ __align__(16) ushort Om[64 * 64];    // 8 KB (mh half)
  __shared__ __align__(16) ushort PhT[128 * 32];  // 8 KB
  __shared__ __align__(16) ushort Vts[80 * 32];   // 5 KB
  __shared__ float offs[32];
  const int tid = threadIdx.x;
  const int bh = blockIdx.x, mh = blockIdx.y;
  const int b = bh / 3, h = bh - b * 3;
  const int wave = tid >> 6, lane = tid & 63;
  const int quad = lane >> 4, l16 = lane & 15;
  const int lr8 = lane >> 3, lk8 = (lane & 7) * 8;
#pragma unroll
  for (int t = 0; t < 2; ++t) {
    const int rb = (t * 4 + wave) * 8;
    gll16(OmT + (size_t)(mh * 64 + rb + lr8) * 64 + lk8, &Om[rb * 64]);
  }
  {
    const int rb = wave * 8;
    const int l = rb + lr8;
    gll16(qkv + (size_t)(b * 197 + l) * 576 + 192 + h * 64 + lk8, &Ks[rb * 64]);
    gll16(qkv + (size_t)(b * 197 + l) * 576 + 384 + h * 64 + lk8, &Vs[rb * 64]);
  }
  floatx4 acc[2][5] = {};
  for (int c = 0; c < 7; ++c) {
    const int l0 = c * 32;
    __syncthreads();   // staged data ready (vmcnt0); PhT/Vts free for rewrite
    if (tid < 64) {
      const int row = tid >> 1, half = tid & 1;
      float s = 0.f;
#pragma unroll
      for (int t = 0; t < 4; ++t) {
        bf16x8 v8 = *(const bf16x8*)&Ks[row * 64 + half * 32 + t * 8];
#pragma unroll
        for (int q = 0; q < 8; ++q) { float xv = bf2f((ushort)v8[q]); s += xv * xv; }
      }
      s += __shfl_xor(s, 1, 64);
      if (half == 0) offs[row] = 0.0625f * s;   // 0.5*scale^2 (scale^2=0.125)
    }
    for (int e = tid; e < 80 * 32; e += 256) {
      const int d = e >> 5, ll = e & 31;
      ushort v = 0;
      if (l0 + ll < 197) {
        if (d < 64) v = Vs[ll * 64 + d];
        else if (d == 64) v = 0x3F80;   // bf16 1.0 (ksum row)
      }
      Vts[d * 32 + ll] = v;
    }
    floatx4 ui[2] = {};
#pragma unroll
    for (int ks = 0; ks < 64; ks += 32) {
      bf16x8 af[2], bfm;
#pragma unroll
      for (int i = 0; i < 2; ++i)
        af[i] = *(const bf16x8*)&Ks[(i * 16 + l16) * 64 + ks + quad * 8];
      bfm = *(const bf16x8*)&Om[(wave * 16 + l16) * 64 + ks + quad * 8];
#pragma unroll
      for (int i = 0; i < 2; ++i)
        ui[i] = __builtin_amdgcn_mfma_f32_16x16x32_bf16(af[i], bfm, ui[i], 0, 0, 0);
    }
    __syncthreads();   // phase-2 LDS reads done
    {
      const int mloc = wave * 16 + l16;
#pragma unroll
      for (int i = 0; i < 2; ++i) {
#pragma unroll
        for (int r = 0; r < 4; ++r) {
          const int ll = i * 16 + quad * 4 + r;
          float ep = 0.f, em = 0.f;
          if (l0 + ll < 197) {
            const float off = offs[ll];
            const float u = ui[i][r];
            ep = __expf(u - off) * 0.0625f;
            em = __expf(-u - off) * 0.0625f;
          }
          PhT[mloc * 32 + ll] = f2bf(ep);
          PhT[(64 + mloc) * 32 + ll] = f2bf(em);
        }
      }
    }
    if (c + 1 < 7) {
      const int rb = wave * 8;
      const int l = (c + 1) * 32 + rb + lr8;
      gll16(qkv + (size_t)(b * 197 + l) * 576 + 192 + h * 64 + lk8, &Ks[rb * 64]);
      gll16(qkv + (size_t)(b * 197 + l) * 576 + 384 + h * 64 + lk8, &Vs[rb * 64]);
    }
    __syncthreads();   // PhT/Vts visible (also drains staging; harmless)
    bf16x8 af[2], bf[5];
#pragma unroll
    for (int i = 0; i < 2; ++i)
      af[i] = *(const bf16x8*)&PhT[(wave * 32 + i * 16 + l16) * 32 + quad * 8];
#pragma unroll
    for (int j = 0; j < 5; ++j)
      bf[j] = *(const bf16x8*)&Vts[(j * 16 + l16) * 32 + quad * 8];
#pragma unroll
    for (int i = 0; i < 2; ++i)
#pragma unroll
      for (int j = 0; j < 5; ++j)
        acc[i][j] = __builtin_amdgcn_mfma_f32_16x16x32_bf16(af[i], bf[j], acc[i][j], 0, 0, 0);
  }
#pragma unroll
  for (int i = 0; i < 2; ++i) {
    const int prow0 = wave * 32 + i * 16 + quad * 4;
    const int f0 = (prow0 < 64) ? (mh * 64 + prow0) : (128 + mh * 64 + prow0 - 64);
#pragma unroll
    for (int j = 0; j < 5; ++j) {
      const int d = j * 16 + l16;
      short4v pk;
#pragma unroll
      for (int r = 0; r < 4; ++r) pk[r] = (short)f2bf(acc[i][j][r]);
      *(short4v*)(KVt + ((size_t)bh * 80 + d) * 256 + f0) = pk;
    }
  }
}

// =========== fused FAVOR-Q + attn: out = Z * (phiQ @ KVt^T) ===========
// grid (2 l-tiles, 192 bh). phiQ computed into LDS (Q/Om staged aliased inside),
// then 8 m-chunks of MFMA vs KVt rows (dbuf staging). z from ksum col (d=64).
__global__ __launch_bounds__(256) void attn_fused(
    const ushort* __restrict__ qkv, const ushort* __restrict__ OmT,
    const ushort* __restrict__ KVt, ushort* __restrict__ OUT)
{
  __shared__ __align__(16) ushort Phi[128 * PHIRS];  // 66 KB; [0:8K)=Qs, [8K:16K)=Om
  __shared__ __align__(16) ushort Bs[2][80 * 32];    // 10 KB
  __shared__ float offs[128];
  __shared__ float zs[128];
  ushort* Qs = Phi;
  ushort* Om = Phi + 128 * 64;
  const int tid = threadIdx.x;
  const int bx = blockIdx.x, bh = blockIdx.y;
  const int b = bh / 3, h = bh - b * 3;
  const int wave = tid >> 6, lane = tid & 63;
  const int wm = (wave >> 1) * 64, wn = (wave & 1) * 64;
  const int quad = lane >> 4, l16 = lane & 15;
  const int lr8 = lane >> 3, lk8 = (lane & 7) * 8;
  const int lrow = lane >> 2, lk = (lane & 3) * 8;
#pragma unroll
  for (int t = 0; t < 4; ++t) {
    const int rb = (t * 4 + wave) * 8;
    const int l = bx * 128 + rb + lr8;
    gll16(qkv + (size_t)(b * 197 + l) * 576 + h * 64 + lk8, &Qs[rb * 64]);
    gll16(OmT + (size_t)(rb + lr8) * 64 + lk8, &Om[rb * 64]);
  }
  __syncthreads();
  {
    const int row = tid >> 1, half = tid & 1;
    float s = 0.f;
#pragma unroll
    for (int t = 0; t < 4; ++t) {
      bf16x8 v8 = *(const bf16x8*)&Qs[row * 64 + half * 32 + t * 8];
#pragma unroll
      for (int q = 0; q < 8; ++q) { float xv = bf2f((ushort)v8[q]); s += xv * xv; }
    }
    s += __shfl_xor(s, 1, 64);
    if (half == 0) offs[row] = 0.0625f * s;
  }
  floatx4 uacc[4][4] = {};
#pragma unroll
  for (int ks = 0; ks < 64; ks += 32) {
    bf16x8 af[4], bf[4];
#pragma unroll
    for (int i = 0; i < 4; ++i) {
      af[i] = *(const bf16x8*)&Qs[(wm + i * 16 + l16) * 64 + ks + quad * 8];
      bf[i] = *(const bf16x8*)&Om[(wn + i * 16 + l16) * 64 + ks + quad * 8];
    }
#pragma unroll
    for (int i = 0; i < 4; ++i)
#pragma unroll
      for (int j = 0; j < 4; ++j)
        uacc[i][j] = __builtin_amdgcn_mfma_f32_16x16x32_bf16(af[i], bf[j], uacc[i][j], 0, 0, 0);
  }
  __syncthreads();   // Qs/Om reads done -> Phi overwrite legal
#pragma unroll
  for (int i = 0; i < 4; ++i) {
#pragma unroll
    for (int r = 0; r < 4; ++r) {
      const int l = wm + i * 16 + quad * 4 + r;
      const float off = offs[l];
#pragma unroll
      for (int j = 0; j < 4; ++j) {
        const int m = wn + j * 16 + l16;
        const float u = uacc[i][j][r];
        Phi[l * PHIRS + m]       = f2bf(__expf(u - off)  * 0.0625f);
        Phi[l * PHIRS + m + 128] = f2bf(__expf(-u - off) * 0.0625f);
      }
    }
  }
  const ushort* Bp = KVt + (size_t)bh * 80 * 256;
  gll16(Bp + (size_t)(wave * 16 + lrow) * 256 + lk, &Bs[0][wave * 16 * 32]);
  if (wave == 0) gll16(Bp + (size_t)(64 + lrow) * 256 + lk, &Bs[0][64 * 32]);
  floatx4 acc[2][5] = {};
  for (int c = 0; c < 8; ++c) {
    const int cur = c & 1;
    __syncthreads();   // Phi visible (c=0) + Bs staging drained + dbuf guard
    if (c + 1 < 8) {
      const int m0 = (c + 1) * 32, nxt = cur ^ 1;
      gll16(Bp + (size_t)(wave * 16 + lrow) * 256 + m0 + lk, &Bs[nxt][wave * 16 * 32]);
      if (wave == 0) gll16(Bp + (size_t)(64 + lrow) * 256 + m0 + lk, &Bs[nxt][64 * 32]);
    }
    const int m0 = c * 32;
    bf16x8 af[2], bf[5];
#pragma unroll
    for (int i = 0; i < 2; ++i)
      af[i] = *(const bf16x8*)&Phi[(wave * 32 + i * 16 + l16) * PHIRS + m0 + quad * 8];
#pragma unroll
    for (int j = 0; j < 5; ++j)
      bf[j] = *(const bf16x8*)&Bs[cur][(j * 16 + l16) * 32 + quad * 8];
#pragma unroll
    for (int i = 0; i < 2; ++i)
#pragma unroll
      for (int j = 0; j < 5; ++j)
        acc[i][j] = __builtin_amdgcn_mfma_f32_16x16x32_bf16(af[i], bf[j], acc[i][j], 0, 0, 0);
  }
  if (l16 == 0) {
#pragma unroll
    for (int i = 0; i < 2; ++i)
#pragma unroll
      for (int r = 0; r < 4; ++r)
        zs[wave * 32 + i * 16 + quad * 4 + r] = acc[i][4][r];
  }
  __syncthreads();
#pragma unroll
  for (int i = 0; i < 2; ++i) {
#pragma unroll
    for (int r = 0; r < 4; ++r) {
      const int ll = wave * 32 + i * 16 + quad * 4 + r;
      const int l = bx * 128 + ll;
      if (l >= 197) continue;
      const float z = 1.f / (zs[ll] + 1e-6f);
#pragma unroll
      for (int j = 0; j < 4; ++j)
        OUT[(size_t)(b * 197 + l) * 192 + h * 64 + j * 16 + l16] =
            f2bf(acc[i][j][r] * z);
    }
  }
}

// ---------------- weight pre-conversion ----------------
__global__ void conv_qkv(const float* __restrict__ Wq, const float* __restrict__ Wk,
                         const float* __restrict__ Wv, const float* __restrict__ bq,
                         const float* __restrict__ bk, const float* __restrict__ bv,
                         ushort* __restrict__ dst, float* __restrict__ bdst) {
  const int l = blockIdx.y;
  const int e = blockIdx.x * 256 + threadIdx.x;   // < 576*192
  const int n = e / 192, k = e - n * 192;
  const float* src;
  if (n < 192)      src = Wq + (size_t)l * 36864 + n * 192;
  else if (n < 384) src = Wk + (size_t)l * 36864 + (n - 192) * 192;
  else              src = Wv + (size_t)l * 36864 + (n - 384) * 192;
  dst[(size_t)l * 640 * 192 + e] = f2bf(src[k]);
  if (e < 576) {
    float bvv;
    if (e < 192)      bvv = bq[l * 192 + e];
    else if (e < 384) bvv = bk[l * 192 + e - 192];
    else              bvv = bv[l * 192 + e - 384];
    bdst[l * 576 + e] = bvv;
  }
}

__global__ void conv_pad(const float* __restrict__ src, ushort* __restrict__ dst,
                         int NK, int padNK) {
  const int l = blockIdx.y;
  const int e = blockIdx.x * 256 + threadIdx.x;
  if (e < NK) dst[(size_t)l * padNK + e] = f2bf(src[(size_t)l * NK + e]);
}

// omega [l][64 d][128 m] -> OmT' [l][128 m][64 d] * sqrt(temp)
__global__ void conv_omt(const float* __restrict__ om, ushort* __restrict__ dst) {
  const int l = blockIdx.y;
  const int e = blockIdx.x * 256 + threadIdx.x;   // < 8192
  const int m = e >> 6, d = e & 63;
  dst[(size_t)l * 8192 + e] = f2bf(0.35355339059327379f * om[(size_t)l * 8192 + d * 128 + m]);
}

// ---------------- im2col (fp32 in -> bf16 out) ----------------
__global__ __launch_bounds__(256) void im2col_kernel(
    const float* __restrict__ X, ushort* __restrict__ Apd)
{
  const int bp = blockIdx.x;
  const int b = bp / NPATCH, p = bp - b * NPATCH;
  const int gh = p / 14, gw = p - gh * 14;
  for (int e = threadIdx.x; e < KPATCH; e += 256) {
    const int c = e >> 8, rem = e & 255, ph = rem >> 4, pw = rem & 15;
    Apd[(size_t)bp * KPATCH + e] =
        f2bf(X[((size_t)(b * 3 + c) * 224 + gh * 16 + ph) * 224 + gw * 16 + pw]);
  }
}

// ---------------- assemble tokens ----------------
__global__ __launch_bounds__(256) void assemble_kernel(
    const ushort* __restrict__ TK, const float* __restrict__ g,
    const float* __restrict__ bt, const float* __restrict__ cls,
    const float* __restrict__ pos, ushort* __restrict__ XC)
{
  const int w = threadIdx.x >> 6, lane = threadIdx.x & 63;
  const int row = blockIdx.x * 4 + w;
  const int b = row / LLEN, l = row - b * LLEN;
  float o0, o1, o2;
  if (l == 0) {
    o0 = cls[lane]; o1 = cls[lane + 64]; o2 = cls[lane + 128];
  } else {
    const ushort* tp = TK + (size_t)(b * NPATCH + l - 1) * DMODEL;
    const float x0 = bf2f(tp[lane]), x1 = bf2f(tp[lane + 64]), x2 = bf2f(tp[lane + 128]);
    const float s  = wave_reduce_sum(x0 + x1 + x2);
    const float sq = wave_reduce_sum(x0 * x0 + x1 * x1 + x2 * x2);
    const float mu = s * (1.f / 192.f);
    const float var = sq * (1.f / 192.f) - mu * mu;
    const float rs = rsqrtf(var + 1e-5f);
    o0 = (x0 - mu) * rs * g[lane]       + bt[lane];
    o1 = (x1 - mu) * rs * g[lane + 64]  + bt[lane + 64];
    o2 = (x2 - mu) * rs * g[lane + 128] + bt[lane + 128];
  }
  o0 += pos[l * DMODEL + lane];
  o1 += pos[l * DMODEL + lane + 64];
  o2 += pos[l * DMODEL + lane + 128];
  ushort* xp = XC + (size_t)row * DMODEL;
  xp[lane] = f2bf(o0); xp[lane + 64] = f2bf(o1); xp[lane + 128] = f2bf(o2);
}

// ---------------- fused: xc = LN(xc + ab)  (bias already in ab) ----------------
__global__ __launch_bounds__(256) void ln1_fused(
    ushort* __restrict__ XC, const ushort* __restrict__ AB,
    const float* __restrict__ g, const float* __restrict__ bt)
{
  const int w = threadIdx.x >> 6, lane = threadIdx.x & 63;
  const int row = blockIdx.x * 4 + w;
  ushort* xp = XC + (size_t)row * DMODEL;
  const ushort* ap = AB + (size_t)row * DMODEL;
  const float x0 = bf2f(xp[lane])       + bf2f(ap[lane]);
  const float x1 = bf2f(xp[lane + 64])  + bf2f(ap[lane + 64]);
  const float x2 = bf2f(xp[lane + 128]) + bf2f(ap[lane + 128]);
  const float s  = wave_reduce_sum(x0 + x1 + x2);
  const float sq = wave_reduce_sum(x0 * x0 + x1 * x1 + x2 * x2);
  const float mu = s * (1.f / 192.f);
  const float var = sq * (1.f / 192.f) - mu * mu;
  const float rs = rsqrtf(var + 1e-5f);
  xp[lane]       = f2bf((x0 - mu) * rs * g[lane]       + bt[lane]);
  xp[lane + 64]  = f2bf((x1 - mu) * rs * g[lane + 64]  + bt[lane + 64]);
  xp[lane + 128] = f2bf((x2 - mu) * rs * g[lane + 128] + bt[lane + 128]);
}

// ---------------- fused: xc = LNb(LN2(xc + ab)) ----------------
__global__ __launch_bounds__(256) void ln2_fused(
    ushort* __restrict__ XC, const ushort* __restrict__ AB,
    const float* __restrict__ ga, const float* __restrict__ ba,
    const float* __restrict__ gb, const float* __restrict__ bb)
{
  const int w = threadIdx.x >> 6, lane = threadIdx.x & 63;
  const int row = blockIdx.x * 4 + w;
  ushort* xp = XC + (size_t)row * DMODEL;
  const ushort* ap = AB + (size_t)row * DMODEL;
  float x0 = bf2f(xp[lane])       + bf2f(ap[lane]);
  float x1 = bf2f(xp[lane + 64])  + bf2f(ap[lane + 64]);
  float x2 = bf2f(xp[lane + 128]) + bf2f(ap[lane + 128]);
  {
    const float s  = wave_reduce_sum(x0 + x1 + x2);
    const float sq = wave_reduce_sum(x0 * x0 + x1 * x1 + x2 * x2);
    const float mu = s * (1.f / 192.f);
    const float var = sq * (1.f / 192.f) - mu * mu;
    const float rs = rsqrtf(var + 1e-5f);
    x0 = (x0 - mu) * rs * ga[lane]       + ba[lane];
    x1 = (x1 - mu) * rs * ga[lane + 64]  + ba[lane + 64];
    x2 = (x2 - mu) * rs * ga[lane + 128] + ba[lane + 128];
  }
  const float s  = wave_reduce_sum(x0 + x1 + x2);
  const float sq = wave_reduce_sum(x0 * x0 + x1 * x1 + x2 * x2);
  const float mu = s * (1.f / 192.f);
  const float var = sq * (1.f / 192.f) - mu * mu;
  const float rs = rsqrtf(var + 1e-5f);
  xp[lane]       = f2bf((x0 - mu) * rs * gb[lane]       + bb[lane]);
  xp[lane + 64]  = f2bf((x1 - mu) * rs * gb[lane + 64]  + bb[lane + 64]);
  xp[lane + 128] = f2bf((x2 - mu) * rs * gb[lane + 128] + bb[lane + 128]);
}

// ---------------- pool + head ----------------
__global__ __launch_bounds__(192) void pool_kernel(
    const ushort* __restrict__ XC, float* __restrict__ Zp)
{
  const int b = blockIdx.x, d = threadIdx.x;
  float s = 0.f;
#pragma unroll 4
  for (int l = 0; l < LLEN; ++l) s += bf2f(XC[(size_t)(b * LLEN + l) * DMODEL + d]);
  Zp[b * DMODEL + d] = s * (1.f / 197.f);
}

__global__ __launch_bounds__(256) void head_kernel(
    const float* __restrict__ Zp, const float* __restrict__ HW,
    const float* __restrict__ HB, float* __restrict__ OUTp)
{
  const int n = blockIdx.x * 256 + threadIdx.x;
  const int b = blockIdx.y;
  if (n < NCLS) {
    const float* z = Zp + b * DMODEL;
    const float* w = HW + (size_t)n * DMODEL;
    float s = HB[n];
#pragma unroll 4
    for (int d = 0; d < DMODEL; ++d) s = fmaf(z[d], w[d], s);
    OUTp[(size_t)b * NCLS + n] = s;
  }
}

// ---------------- host orchestration ----------------
extern "C" void kernel_launch(void* const* d_in, const int* in_sizes, int n_in,
                              void* d_out, int out_size, void* d_ws, size_t ws_size,
                              hipStream_t stream) {
  const float* x        = (const float*)d_in[0];
  const float* patch_w  = (const float*)d_in[1];
  const float* patch_b  = (const float*)d_in[2];
  const float* pe_ln_g  = (const float*)d_in[3];
  const float* pe_ln_b  = (const float*)d_in[4];
  const float* cls_tok  = (const float*)d_in[5];
  const float* pos_emb  = (const float*)d_in[6];
  const float* Wq = (const float*)d_in[7];
  const float* bq = (const float*)d_in[8];
  const float* Wk = (const float*)d_in[9];
  const float* bk = (const float*)d_in[10];
  const float* Wv = (const float*)d_in[11];
  const float* bv = (const float*)d_in[12];
  const float* Wo = (const float*)d_in[13];
  const float* bo = (const float*)d_in[14];
  const float* ln1_g = (const float*)d_in[15];
  const float* ln1_b = (const float*)d_in[16];
  const float* ln2_g = (const float*)d_in[17];
  const float* ln2_b = (const float*)d_in[18];
  const float* lnb_g = (const float*)d_in[19];
  const float* lnb_b = (const float*)d_in[20];
  const float* W1 = (const float*)d_in[21];
  const float* b1 = (const float*)d_in[22];
  const float* W2 = (const float*)d_in[23];
  const float* b2 = (const float*)d_in[24];
  const float* omega  = (const float*)d_in[25];
  const float* head_w = (const float*)d_in[26];
  const float* head_b = (const float*)d_in[27];
  float* out = (float*)d_out;
  char* wsb = (char*)d_ws;

  size_t off = 0;
  auto carve = [&](size_t bytes) { size_t o = off; off += (bytes + 255) & ~(size_t)255; return o; };
  ushort* xc     = (ushort*)(wsb + carve((size_t)MPAD * 192 * 2));
  ushort* qkv    = (ushort*)(wsb + carve((size_t)MPAD * 576 * 2));
  ushort* ab     = (ushort*)(wsb + carve((size_t)MPAD * 192 * 2));
  ushort* hidden = (ushort*)(wsb + carve((size_t)MPAD * 768 * 2));   // aliases im2col
  ushort* KVt    = (ushort*)(wsb + carve((size_t)192 * 80 * 256 * 2));
  float*  ZPb    = (float*)(wsb + carve((size_t)64 * 192 * 4));
  float*  bqkv   = (float*)(wsb + carve((size_t)12 * 576 * 4));
  ushort* Wqkv_bf = (ushort*)(wsb + carve((size_t)12 * 640 * 192 * 2));
  ushort* Wo_bf   = (ushort*)(wsb + carve((size_t)12 * 256 * 192 * 2));
  ushort* W1_bf   = (ushort*)(wsb + carve((size_t)12 * 768 * 192 * 2));
  ushort* W2_bf   = (ushort*)(wsb + carve((size_t)12 * 256 * 768 * 2));
  ushort* Wp_bf   = (ushort*)(wsb + carve((size_t)256 * 768 * 2));
  ushort* Om_bf   = (ushort*)(wsb + carve((size_t)12 * 128 * 64 * 2));
  ushort* i2c     = hidden;   // patch GEMM consumes before FF uses hidden

  // ---- pre-conversion ----
  conv_qkv<<<dim3(432, 12), 256, 0, stream>>>(Wq, Wk, Wv, bq, bk, bv, Wqkv_bf, bqkv);
  conv_pad<<<dim3(144, 12), 256, 0, stream>>>(Wo, Wo_bf, 36864, 256 * 192);
  conv_pad<<<dim3(576, 12), 256, 0, stream>>>(W1, W1_bf, 147456, 768 * 192);
  conv_pad<<<dim3(576, 12), 256, 0, stream>>>(W2, W2_bf, 147456, 256 * 768);
  conv_pad<<<dim3(576, 1), 256, 0, stream>>>(patch_w, Wp_bf, 147456, 256 * 768);
  conv_omt<<<dim3(32, 12), 256, 0, stream>>>(omega, Om_bf);

  // ---- patch embedding ----
  im2col_kernel<<<BPROWS, 256, 0, stream>>>(x, i2c);
  gemm_n32<<<dim3(98, 6), 256, 0, stream>>>(i2c, KPATCH, Wp_bf, KPATCH,
      patch_b, ab, DMODEL, KPATCH);
  assemble_kernel<<<BLROWS / 4, 256, 0, stream>>>(ab, pe_ln_g, pe_ln_b,
                                                  cls_tok, pos_emb, xc);

  const int exits[3] = {3, 7, 11};
  for (int i = 0; i < NDEPTH; ++i) {
    // QKV: N=576 -> 9 N-tiles, 891 blocks
    gemm_bf2<<<dim3(99, 9), 256, 0, stream>>>(xc, DMODEL,
        Wqkv_bf + (size_t)i * 640 * 192, DMODEL, bqkv + i * 576,
        qkv, 576, DMODEL, MODE_PLAIN);
    // fused FAVOR-K + V-transpose + KV
    kv_fused<<<dim3(192, 2), 256, 0, stream>>>(qkv,
        Om_bf + (size_t)i * 8192, KVt);
    // fused FAVOR-Q + attn
    attn_fused<<<dim3(2, 192), 256, 0, stream>>>(qkv,
        Om_bf + (size_t)i * 8192, KVt, ab);
    // O-proj: 128x32 tiles, 6 N-tiles -> 594 blocks, direct bf16 + bias
    gemm_n32<<<dim3(99, 6), 256, 0, stream>>>(ab, DMODEL,
        Wo_bf + (size_t)i * 256 * 192, DMODEL, bo + i * DMODEL,
        qkv, DMODEL, DMODEL);   // reuse qkv buffer as O-proj out (dead now)
    ln1_fused<<<BLROWS / 4, 256, 0, stream>>>(xc, qkv,
        ln1_g + i * DMODEL, ln1_b + i * DMODEL);
    // W1: N=768 -> 12 N-tiles, 1188 blocks
    gemm_bf2<<<dim3(99, 12), 256, 0, stream>>>(xc, DMODEL,
        W1_bf + (size_t)i * 768 * 192, DMODEL, b1 + i * FFDIM,
        hidden, FFDIM, DMODEL, MODE_RELU);
    // W2: 128x32 tiles, 594 blocks, direct bf16 + bias
    gemm_n32<<<dim3(99, 6), 256, 0, stream>>>(hidden, FFDIM,
        W2_bf + (size_t)i * 256 * 768, FFDIM, b2 + i * DMODEL,
        ab, DMODEL, FFDIM);
    ln2_fused<<<BLROWS / 4, 256, 0, stream>>>(xc, ab,
        ln2_g + i * DMODEL, ln2_b + i * DMODEL,
        lnb_g + i * DMODEL, lnb_b + i * DMODEL);

    for (int j = 0; j < 3; ++j) {
      if (i == exits[j]) {
        pool_kernel<<<BB, 192, 0, stream>>>(xc, ZPb);
        head_kernel<<<dim3(4, BB), 256, 0, stream>>>(
            ZPb, head_w + (size_t)j * NCLS * DMODEL, head_b + (size_t)j * NCLS,
            out + (size_t)j * BB * NCLS);
      }
    }
  }
}

// Round 10
// 1607.510 us; speedup vs baseline: 1.0451x; 1.0451x over previous
//
#include <hip/hip_runtime.h>
#include <math.h>

// ---------------- problem constants ----------------
#define BB     64
#define LLEN   197
#define BLROWS 12608      // BB*LLEN
#define MPAD   12672      // BLROWS padded to 99*128
#define DMODEL 192
#define NHEAD  3
#define DHEAD  64
#define M2FEAT 256
#define FFDIM  768
#define NDEPTH 12
#define NCLS   1000
#define NPATCH 196
#define BPROWS 12544      // BB*NPATCH (= 98*128 exactly)
#define KPATCH 768
#define PHIRS  264        // Phi LDS row stride (256 + 8 pad, 16B-aligned)

#define MODE_PLAIN 0
#define MODE_RELU  1
#define MODE_PART  3      // write fp32 partial (split-K), no bias

typedef unsigned short ushort;
typedef __attribute__((ext_vector_type(8))) short bf16x8;
typedef __attribute__((ext_vector_type(4))) float floatx4;
typedef __attribute__((ext_vector_type(4))) short short4v;

__device__ __forceinline__ float wave_reduce_sum(float v) {
#pragma unroll
  for (int s = 32; s > 0; s >>= 1) v += __shfl_xor(v, s, 64);
  return v;
}
__device__ __forceinline__ ushort f2bf(float f) {  // RNE fp32->bf16
  unsigned u = __float_as_uint(f);
  return (ushort)((u + 0x7fffu + ((u >> 16) & 1u)) >> 16);
}
__device__ __forceinline__ float bf2f(ushort u) {
  return __uint_as_float(((unsigned)u) << 16);
}
// async global->LDS, 16 B per lane; LDS dest wave-uniform (HW adds lane*16)
__device__ __forceinline__ void gll16(const ushort* g, ushort* l) {
  __builtin_amdgcn_global_load_lds(
      (const __attribute__((address_space(1))) void*)g,
      (__attribute__((address_space(3))) void*)l, 16, 0, 0);
}

// =========== bf16 GEMM, 128x128 tile, dbuf LDS (wide-N GEMMs) ===========
// block 256 = 4 waves (2x2 of 64x64), 16 MFMA/wave/barrier. bias (+relu) out.
__global__ __launch_bounds__(256) void gemm_128(
    const ushort* __restrict__ A, int lda,
    const ushort* __restrict__ W, int ldw,
    const float* __restrict__ bias,
    ushort* __restrict__ C, int ldc, int Ndim, int Kdim, int mode)
{
  __shared__ __align__(16) ushort As[2][128 * 32];   // 16 KB
  __shared__ __align__(16) ushort Ws[2][128 * 32];   // 16 KB
  const int tid = threadIdx.x;
  const int bm = blockIdx.x, bn = blockIdx.y;
  const int wave = tid >> 6, lane = tid & 63;
  const int wm = (wave >> 1) * 64, wn = (wave & 1) * 64;
  const int quad = lane >> 4, l16 = lane & 15;
  const int lrow = lane >> 2, lk = (lane & 3) * 8;
  const ushort* Ap = A + (size_t)(bm * 128) * lda;
  const ushort* Wp = W + (size_t)(bn * 128) * ldw;
  floatx4 acc[4][4] = {};
  const int nT = Kdim >> 5;
#pragma unroll
  for (int t = 0; t < 2; ++t) {
    const int rb = (t * 4 + wave) * 16;
    gll16(Ap + (size_t)(rb + lrow) * lda + lk, &As[0][rb * 32]);
    gll16(Wp + (size_t)(rb + lrow) * ldw + lk, &Ws[0][rb * 32]);
  }
  for (int kt = 0; kt < nT; ++kt) {
    const int cur = kt & 1;
    __syncthreads();                 // drains prefetch(kt) (vmcnt0) + buf reuse
    if (kt + 1 < nT) {
      const int kk = (kt + 1) * 32, nxt = cur ^ 1;
#pragma unroll
      for (int t = 0; t < 2; ++t) {
        const int rb = (t * 4 + wave) * 16;
        gll16(Ap + (size_t)(rb + lrow) * lda + kk + lk, &As[nxt][rb * 32]);
        gll16(Wp + (size_t)(rb + lrow) * ldw + kk + lk, &Ws[nxt][rb * 32]);
      }
    }
    bf16x8 af[4], bf[4];
#pragma unroll
    for (int i = 0; i < 4; ++i) {
      af[i] = *(const bf16x8*)&As[cur][(wm + i * 16 + l16) * 32 + quad * 8];
      bf[i] = *(const bf16x8*)&Ws[cur][(wn + i * 16 + l16) * 32 + quad * 8];
    }
#pragma unroll
    for (int i = 0; i < 4; ++i)
#pragma unroll
      for (int j = 0; j < 4; ++j)
        acc[i][j] = __builtin_amdgcn_mfma_f32_16x16x32_bf16(af[i], bf[j], acc[i][j], 0, 0, 0);
  }
#pragma unroll
  for (int j = 0; j < 4; ++j) {
    const int col = bn * 128 + wn + j * 16 + l16;
    if (col >= Ndim) continue;
    const float bv = bias[col];
#pragma unroll
    for (int i = 0; i < 4; ++i)
#pragma unroll
      for (int r = 0; r < 4; ++r) {
        const int grow = bm * 128 + wm + i * 16 + quad * 4 + r;
        float o = acc[i][j][r] + bv;
        if (mode == MODE_RELU) o = fmaxf(o, 0.f);
        C[(size_t)grow * ldc + col] = f2bf(o);
      }
  }
}

// =========== bf16 GEMM, 128x64 tile, dbuf LDS, optional split-K ===========
// block 256 = 4 waves (2x2 of 64x32). blockIdx.z = K-chunk (split-K);
// MODE_PART writes fp32 partials P[z][row][ldc]; else bf16 C with bias(+relu).
__global__ __launch_bounds__(256) void gemm_bf2(
    const ushort* __restrict__ A, int lda,
    const ushort* __restrict__ W, int ldw,
    const float* __restrict__ bias,
    ushort* __restrict__ C, float* __restrict__ P, int ldc,
    int Kchunk, int mode)
{
  __shared__ __align__(16) ushort As[2][128 * 32];   // 16 KB
  __shared__ __align__(16) ushort Ws[2][64 * 32];    // 8 KB
  const int tid = threadIdx.x;
  const int bm = blockIdx.x, bn = blockIdx.y, bz = blockIdx.z;
  const int wave = tid >> 6, lane = tid & 63;
  const int wm = (wave >> 1) * 64, wn = (wave & 1) * 32;
  const int quad = lane >> 4, l16 = lane & 15;
  const int lrow = lane >> 2, lk = (lane & 3) * 8;
  const ushort* Ap = A + (size_t)(bm * 128) * lda + bz * Kchunk;
  const ushort* Wp = W + (size_t)(bn * 64) * ldw + bz * Kchunk;
  floatx4 acc[4][2] = {};
  const int nT = Kchunk >> 5;
#pragma unroll
  for (int t = 0; t < 2; ++t) {
    const int rb = (t * 4 + wave) * 16;
    gll16(Ap + (size_t)(rb + lrow) * lda + lk, &As[0][rb * 32]);
  }
  gll16(Wp + (size_t)(wave * 16 + lrow) * ldw + lk, &Ws[0][wave * 16 * 32]);
  for (int kt = 0; kt < nT; ++kt) {
    const int cur = kt & 1;
    __syncthreads();                 // drains prefetch(kt) (vmcnt0) + buf reuse
    if (kt + 1 < nT) {
      const int kk = (kt + 1) * 32, nxt = cur ^ 1;
#pragma unroll
      for (int t = 0; t < 2; ++t) {
        const int rb = (t * 4 + wave) * 16;
        gll16(Ap + (size_t)(rb + lrow) * lda + kk + lk, &As[nxt][rb * 32]);
      }
      gll16(Wp + (size_t)(wave * 16 + lrow) * ldw + kk + lk, &Ws[nxt][wave * 16 * 32]);
    }
    bf16x8 af[4], bf[2];
#pragma unroll
    for (int i = 0; i < 4; ++i)
      af[i] = *(const bf16x8*)&As[cur][(wm + i * 16 + l16) * 32 + quad * 8];
#pragma unroll
    for (int j = 0; j < 2; ++j)
      bf[j] = *(const bf16x8*)&Ws[cur][(wn + j * 16 + l16) * 32 + quad * 8];
#pragma unroll
    for (int i = 0; i < 4; ++i)
#pragma unroll
      for (int j = 0; j < 2; ++j)
        acc[i][j] = __builtin_amdgcn_mfma_f32_16x16x32_bf16(af[i], bf[j], acc[i][j], 0, 0, 0);
  }
  if (mode == MODE_PART) {
#pragma unroll
    for (int j = 0; j < 2; ++j) {
      const int col = bn * 64 + wn + j * 16 + l16;
#pragma unroll
      for (int i = 0; i < 4; ++i)
#pragma unroll
        for (int r = 0; r < 4; ++r) {
          const int grow = bm * 128 + wm + i * 16 + quad * 4 + r;
          P[((size_t)bz * MPAD + grow) * ldc + col] = acc[i][j][r];
        }
    }
  } else {
#pragma unroll
    for (int j = 0; j < 2; ++j) {
      const int col = bn * 64 + wn + j * 16 + l16;
      const float bv = bias[col];
#pragma unroll
      for (int i = 0; i < 4; ++i)
#pragma unroll
        for (int r = 0; r < 4; ++r) {
          const int grow = bm * 128 + wm + i * 16 + quad * 4 + r;
          float o = acc[i][j][r] + bv;
          if (mode == MODE_RELU) o = fmaxf(o, 0.f);
          C[(size_t)grow * ldc + col] = f2bf(o);
        }
    }
  }
}

// =========== fused FAVOR-K + V-transpose + KV accumulation ===========
// grid (192 bh, 2 mh). Per 32-token chunk: u = K*scale @ Om_half^T (MFMA),
// phi = exp(+-u - off) -> LDS transposed [128 prow][32 l]; V transposed in LDS;
// KV[prow][d] += phiT @ VtT via MFMA. Out KVt [bh][80 d][256 f] (d=64 row: ksum).
__global__ __launch_bounds__(256) void kv_fused(
    const ushort* __restrict__ qkv, const ushort* __restrict__ OmT,
    ushort* __restrict__ KVt)
{
  __shared__ __align__(16) ushort Ks[32 * 64];    // 4 KB
  __shared__ __align__(16) ushort Vs[32 * 64];    // 4 KB
  __shared__ __align__(16) ushort Om[64 * 64];    // 8 KB (mh half)
  __shared__ __align__(16) ushort PhT[128 * 32];  // 8 KB
  __shared__ __align__(16) ushort Vts[80 * 32];   // 5 KB
  __shared__ float offs[32];
  const int tid = threadIdx.x;
  const int bh = blockIdx.x, mh = blockIdx.y;
  const int b = bh / 3, h = bh - b * 3;
  const int wave = tid >> 6, lane = tid & 63;
  const int quad = lane >> 4, l16 = lane & 15;
  const int lr8 = lane >> 3, lk8 = (lane & 7) * 8;
#pragma unroll
  for (int t = 0; t < 2; ++t) {
    const int rb = (t * 4 + wave) * 8;
    gll16(OmT + (size_t)(mh * 64 + rb + lr8) * 64 + lk8, &Om[rb * 64]);
  }
  {
    const int rb = wave * 8;
    const int l = rb + lr8;
    gll16(qkv + (size_t)(b * 197 + l) * 576 + 192 + h * 64 + lk8, &Ks[rb * 64]);
    gll16(qkv + (size_t)(b * 197 + l) * 576 + 384 + h * 64 + lk8, &Vs[rb * 64]);
  }
  floatx4 acc[2][5] = {};
  for (int c = 0; c < 7; ++c) {
    const int l0 = c * 32;
    __syncthreads();   // staged data ready (vmcnt0); PhT/Vts free for rewrite
    if (tid < 64) {
      const int row = tid >> 1, half = tid & 1;
      float s = 0.f;
#pragma unroll
      for (int t = 0; t < 4; ++t) {
        bf16x8 v8 = *(const bf16x8*)&Ks[row * 64 + half * 32 + t * 8];
#pragma unroll
        for (int q = 0; q < 8; ++q) { float xv = bf2f((ushort)v8[q]); s += xv * xv; }
      }
      s += __shfl_xor(s, 1, 64);
      if (half == 0) offs[row] = 0.0625f * s;   // 0.5*scale^2 (scale^2=0.125)
    }
    for (int e = tid; e < 80 * 32; e += 256) {
      const int d = e >> 5, ll = e & 31;
      ushort v = 0;
      if (l0 + ll < 197) {
        if (d < 64) v = Vs[ll * 64 + d];
        else if (d == 64) v = 0x3F80;   // bf16 1.0 (ksum row)
      }
      Vts[d * 32 + ll] = v;
    }
    floatx4 ui[2] = {};
#pragma unroll
    for (int ks = 0; ks < 64; ks += 32) {
      bf16x8 af[2], bfm;
#pragma unroll
      for (int i = 0; i < 2; ++i)
        af[i] = *(const bf16x8*)&Ks[(i * 16 + l16) * 64 + ks + quad * 8];
      bfm = *(const bf16x8*)&Om[(wave * 16 + l16) * 64 + ks + quad * 8];
#pragma unroll
      for (int i = 0; i < 2; ++i)
        ui[i] = __builtin_amdgcn_mfma_f32_16x16x32_bf16(af[i], bfm, ui[i], 0, 0, 0);
    }
    __syncthreads();   // phase-2 LDS reads done
    {
      const int mloc = wave * 16 + l16;
#pragma unroll
      for (int i = 0; i < 2; ++i) {
#pragma unroll
        for (int r = 0; r < 4; ++r) {
          const int ll = i * 16 + quad * 4 + r;
          float ep = 0.f, em = 0.f;
          if (l0 + ll < 197) {
            const float off = offs[ll];
            const float u = ui[i][r];
            ep = __expf(u - off) * 0.0625f;
            em = __expf(-u - off) * 0.0625f;
          }
          PhT[mloc * 32 + ll] = f2bf(ep);
          PhT[(64 + mloc) * 32 + ll] = f2bf(em);
        }
      }
    }
    if (c + 1 < 7) {
      const int rb = wave * 8;
      const int l = (c + 1) * 32 + rb + lr8;
      gll16(qkv + (size_t)(b * 197 + l) * 576 + 192 + h * 64 + lk8, &Ks[rb * 64]);
      gll16(qkv + (size_t)(b * 197 + l) * 576 + 384 + h * 64 + lk8, &Vs[rb * 64]);
    }
    __syncthreads();   // PhT/Vts visible (also drains staging; harmless)
    bf16x8 af[2], bf[5];
#pragma unroll
    for (int i = 0; i < 2; ++i)
      af[i] = *(const bf16x8*)&PhT[(wave * 32 + i * 16 + l16) * 32 + quad * 8];
#pragma unroll
    for (int j = 0; j < 5; ++j)
      bf[j] = *(const bf16x8*)&Vts[(j * 16 + l16) * 32 + quad * 8];
#pragma unroll
    for (int i = 0; i < 2; ++i)
#pragma unroll
      for (int j = 0; j < 5; ++j)
        acc[i][j] = __builtin_amdgcn_mfma_f32_16x16x32_bf16(af[i], bf[j], acc[i][j], 0, 0, 0);
  }
#pragma unroll
  for (int i = 0; i < 2; ++i) {
    const int prow0 = wave * 32 + i * 16 + quad * 4;
    const int f0 = (prow0 < 64) ? (mh * 64 + prow0) : (128 + mh * 64 + prow0 - 64);
#pragma unroll
    for (int j = 0; j < 5; ++j) {
      const int d = j * 16 + l16;
      short4v pk;
#pragma unroll
      for (int r = 0; r < 4; ++r) pk[r] = (short)f2bf(acc[i][j][r]);
      *(short4v*)(KVt + ((size_t)bh * 80 + d) * 256 + f0) = pk;
    }
  }
}

// =========== fused FAVOR-Q + attn: out = Z * (phiQ @ KVt^T) ===========
// grid (2 l-tiles, 192 bh). phiQ computed into LDS (Q/Om staged aliased inside),
// then 8 m-chunks of MFMA vs KVt rows (dbuf staging). z from ksum col (d=64).
__global__ __launch_bounds__(256) void attn_fused(
    const ushort* __restrict__ qkv, const ushort* __restrict__ OmT,
    const ushort* __restrict__ KVt, ushort* __restrict__ OUT)
{
  __shared__ __align__(16) ushort Phi[128 * PHIRS];  // 66 KB; [0:8K)=Qs, [8K:16K)=Om
  __shared__ __align__(16) ushort Bs[2][80 * 32];    // 10 KB
  __shared__ float offs[128];
  __shared__ float zs[128];
  ushort* Qs = Phi;
  ushort* Om = Phi + 128 * 64;
  const int tid = threadIdx.x;
  const int bx = blockIdx.x, bh = blockIdx.y;
  const int b = bh / 3, h = bh - b * 3;
  const int wave = tid >> 6, lane = tid & 63;
  const int wm = (wave >> 1) * 64, wn = (wave & 1) * 64;
  const int quad = lane >> 4, l16 = lane & 15;
  const int lr8 = lane >> 3, lk8 = (lane & 7) * 8;
  const int lrow = lane >> 2, lk = (lane & 3) * 8;
#pragma unroll
  for (int t = 0; t < 4; ++t) {
    const int rb = (t * 4 + wave) * 8;
    const int l = bx * 128 + rb + lr8;
    gll16(qkv + (size_t)(b * 197 + l) * 576 + h * 64 + lk8, &Qs[rb * 64]);
    gll16(OmT + (size_t)(rb + lr8) * 64 + lk8, &Om[rb * 64]);
  }
  __syncthreads();
  {
    const int row = tid >> 1, half = tid & 1;
    float s = 0.f;
#pragma unroll
    for (int t = 0; t < 4; ++t) {
      bf16x8 v8 = *(const bf16x8*)&Qs[row * 64 + half * 32 + t * 8];
#pragma unroll
      for (int q = 0; q < 8; ++q) { float xv = bf2f((ushort)v8[q]); s += xv * xv; }
    }
    s += __shfl_xor(s, 1, 64);
    if (half == 0) offs[row] = 0.0625f * s;
  }
  floatx4 uacc[4][4] = {};
#pragma unroll
  for (int ks = 0; ks < 64; ks += 32) {
    bf16x8 af[4], bf[4];
#pragma unroll
    for (int i = 0; i < 4; ++i) {
      af[i] = *(const bf16x8*)&Qs[(wm + i * 16 + l16) * 64 + ks + quad * 8];
      bf[i] = *(const bf16x8*)&Om[(wn + i * 16 + l16) * 64 + ks + quad * 8];
    }
#pragma unroll
    for (int i = 0; i < 4; ++i)
#pragma unroll
      for (int j = 0; j < 4; ++j)
        uacc[i][j] = __builtin_amdgcn_mfma_f32_16x16x32_bf16(af[i], bf[j], uacc[i][j], 0, 0, 0);
  }
  __syncthreads();   // Qs/Om reads done -> Phi overwrite legal
#pragma unroll
  for (int i = 0; i < 4; ++i) {
#pragma unroll
    for (int r = 0; r < 4; ++r) {
      const int l = wm + i * 16 + quad * 4 + r;
      const float off = offs[l];
#pragma unroll
      for (int j = 0; j < 4; ++j) {
        const int m = wn + j * 16 + l16;
        const float u = uacc[i][j][r];
        Phi[l * PHIRS + m]       = f2bf(__expf(u - off)  * 0.0625f);
        Phi[l * PHIRS + m + 128] = f2bf(__expf(-u - off) * 0.0625f);
      }
    }
  }
  const ushort* Bp = KVt + (size_t)bh * 80 * 256;
  gll16(Bp + (size_t)(wave * 16 + lrow) * 256 + lk, &Bs[0][wave * 16 * 32]);
  if (wave == 0) gll16(Bp + (size_t)(64 + lrow) * 256 + lk, &Bs[0][64 * 32]);
  floatx4 acc[2][5] = {};
  for (int c = 0; c < 8; ++c) {
    const int cur = c & 1;
    __syncthreads();   // Phi visible (c=0) + Bs staging drained + dbuf guard
    if (c + 1 < 8) {
      const int m0 = (c + 1) * 32, nxt = cur ^ 1;
      gll16(Bp + (size_t)(wave * 16 + lrow) * 256 + m0 + lk, &Bs[nxt][wave * 16 * 32]);
      if (wave == 0) gll16(Bp + (size_t)(64 + lrow) * 256 + m0 + lk, &Bs[nxt][64 * 32]);
    }
    const int m0 = c * 32;
    bf16x8 af[2], bf[5];
#pragma unroll
    for (int i = 0; i < 2; ++i)
      af[i] = *(const bf16x8*)&Phi[(wave * 32 + i * 16 + l16) * PHIRS + m0 + quad * 8];
#pragma unroll
    for (int j = 0; j < 5; ++j)
      bf[j] = *(const bf16x8*)&Bs[cur][(j * 16 + l16) * 32 + quad * 8];
#pragma unroll
    for (int i = 0; i < 2; ++i)
#pragma unroll
      for (int j = 0; j < 5; ++j)
        acc[i][j] = __builtin_amdgcn_mfma_f32_16x16x32_bf16(af[i], bf[j], acc[i][j], 0, 0, 0);
  }
  if (l16 == 0) {
#pragma unroll
    for (int i = 0; i < 2; ++i)
#pragma unroll
      for (int r = 0; r < 4; ++r)
        zs[wave * 32 + i * 16 + quad * 4 + r] = acc[i][4][r];
  }
  __syncthreads();
#pragma unroll
  for (int i = 0; i < 2; ++i) {
#pragma unroll
    for (int r = 0; r < 4; ++r) {
      const int ll = wave * 32 + i * 16 + quad * 4 + r;
      const int l = bx * 128 + ll;
      if (l >= 197) continue;
      const float z = 1.f / (zs[ll] + 1e-6f);
#pragma unroll
      for (int j = 0; j < 4; ++j)
        OUT[(size_t)(b * 197 + l) * 192 + h * 64 + j * 16 + l16] =
            f2bf(acc[i][j][r] * z);
    }
  }
}

// ---------------- weight pre-conversion ----------------
__global__ void conv_qkv(const float* __restrict__ Wq, const float* __restrict__ Wk,
                         const float* __restrict__ Wv, const float* __restrict__ bq,
                         const float* __restrict__ bk, const float* __restrict__ bv,
                         ushort* __restrict__ dst, float* __restrict__ bdst) {
  const int l = blockIdx.y;
  const int e = blockIdx.x * 256 + threadIdx.x;   // < 576*192
  const int n = e / 192, k = e - n * 192;
  const float* src;
  if (n < 192)      src = Wq + (size_t)l * 36864 + n * 192;
  else if (n < 384) src = Wk + (size_t)l * 36864 + (n - 192) * 192;
  else              src = Wv + (size_t)l * 36864 + (n - 384) * 192;
  dst[(size_t)l * 640 * 192 + e] = f2bf(src[k]);
  if (e < 576) {
    float bvv;
    if (e < 192)      bvv = bq[l * 192 + e];
    else if (e < 384) bvv = bk[l * 192 + e - 192];
    else              bvv = bv[l * 192 + e - 384];
    bdst[l * 576 + e] = bvv;
  }
}

__global__ void conv_pad(const float* __restrict__ src, ushort* __restrict__ dst,
                         int NK, int padNK) {
  const int l = blockIdx.y;
  const int e = blockIdx.x * 256 + threadIdx.x;
  if (e < NK) dst[(size_t)l * padNK + e] = f2bf(src[(size_t)l * NK + e]);
}

// omega [l][64 d][128 m] -> OmT' [l][128 m][64 d] * sqrt(temp)
__global__ void conv_omt(const float* __restrict__ om, ushort* __restrict__ dst) {
  const int l = blockIdx.y;
  const int e = blockIdx.x * 256 + threadIdx.x;   // < 8192
  const int m = e >> 6, d = e & 63;
  dst[(size_t)l * 8192 + e] = f2bf(0.35355339059327379f * om[(size_t)l * 8192 + d * 128 + m]);
}

// ---------------- im2col (fp32 in -> bf16 out) ----------------
__global__ __launch_bounds__(256) void im2col_kernel(
    const float* __restrict__ X, ushort* __restrict__ Apd)
{
  const int bp = blockIdx.x;
  const int b = bp / NPATCH, p = bp - b * NPATCH;
  const int gh = p / 14, gw = p - gh * 14;
  for (int e = threadIdx.x; e < KPATCH; e += 256) {
    const int c = e >> 8, rem = e & 255, ph = rem >> 4, pw = rem & 15;
    Apd[(size_t)bp * KPATCH + e] =
        f2bf(X[((size_t)(b * 3 + c) * 224 + gh * 16 + ph) * 224 + gw * 16 + pw]);
  }
}

// ---------------- assemble tokens ----------------
__global__ __launch_bounds__(256) void assemble_kernel(
    const ushort* __restrict__ TK, const float* __restrict__ g,
    const float* __restrict__ bt, const float* __restrict__ cls,
    const float* __restrict__ pos, ushort* __restrict__ XC)
{
  const int w = threadIdx.x >> 6, lane = threadIdx.x & 63;
  const int row = blockIdx.x * 4 + w;
  const int b = row / LLEN, l = row - b * LLEN;
  float o0, o1, o2;
  if (l == 0) {
    o0 = cls[lane]; o1 = cls[lane + 64]; o2 = cls[lane + 128];
  } else {
    const ushort* tp = TK + (size_t)(b * NPATCH + l - 1) * DMODEL;
    const float x0 = bf2f(tp[lane]), x1 = bf2f(tp[lane + 64]), x2 = bf2f(tp[lane + 128]);
    const float s  = wave_reduce_sum(x0 + x1 + x2);
    const float sq = wave_reduce_sum(x0 * x0 + x1 * x1 + x2 * x2);
    const float mu = s * (1.f / 192.f);
    const float var = sq * (1.f / 192.f) - mu * mu;
    const float rs = rsqrtf(var + 1e-5f);
    o0 = (x0 - mu) * rs * g[lane]       + bt[lane];
    o1 = (x1 - mu) * rs * g[lane + 64]  + bt[lane + 64];
    o2 = (x2 - mu) * rs * g[lane + 128] + bt[lane + 128];
  }
  o0 += pos[l * DMODEL + lane];
  o1 += pos[l * DMODEL + lane + 64];
  o2 += pos[l * DMODEL + lane + 128];
  ushort* xp = XC + (size_t)row * DMODEL;
  xp[lane] = f2bf(o0); xp[lane + 64] = f2bf(o1); xp[lane + 128] = f2bf(o2);
}

// ---------------- fused: xc = LN(xc + P0 + P1 + bias) ----------------
__global__ __launch_bounds__(256) void ln1_fused(
    ushort* __restrict__ XC, const float* __restrict__ P,
    const float* __restrict__ bias,
    const float* __restrict__ g, const float* __restrict__ bt)
{
  const int w = threadIdx.x >> 6, lane = threadIdx.x & 63;
  const int row = blockIdx.x * 4 + w;
  ushort* xp = XC + (size_t)row * DMODEL;
  const float* p0 = P + (size_t)row * DMODEL;
  const float* p1 = P + ((size_t)MPAD + row) * DMODEL;
  const float x0 = bf2f(xp[lane])       + p0[lane]       + p1[lane]       + bias[lane];
  const float x1 = bf2f(xp[lane + 64])  + p0[lane + 64]  + p1[lane + 64]  + bias[lane + 64];
  const float x2 = bf2f(xp[lane + 128]) + p0[lane + 128] + p1[lane + 128] + bias[lane + 128];
  const float s  = wave_reduce_sum(x0 + x1 + x2);
  const float sq = wave_reduce_sum(x0 * x0 + x1 * x1 + x2 * x2);
  const float mu = s * (1.f / 192.f);
  const float var = sq * (1.f / 192.f) - mu * mu;
  const float rs = rsqrtf(var + 1e-5f);
  xp[lane]       = f2bf((x0 - mu) * rs * g[lane]       + bt[lane]);
  xp[lane + 64]  = f2bf((x1 - mu) * rs * g[lane + 64]  + bt[lane + 64]);
  xp[lane + 128] = f2bf((x2 - mu) * rs * g[lane + 128] + bt[lane + 128]);
}

// ---------------- fused: xc = LNb(LN2(xc + P0 + P1 + bias)) ----------------
__global__ __launch_bounds__(256) void ln2_fused(
    ushort* __restrict__ XC, const float* __restrict__ P,
    const float* __restrict__ bias,
    const float* __restrict__ ga, const float* __restrict__ ba,
    const float* __restrict__ gb, const float* __restrict__ bb)
{
  const int w = threadIdx.x >> 6, lane = threadIdx.x & 63;
  const int row = blockIdx.x * 4 + w;
  ushort* xp = XC + (size_t)row * DMODEL;
  const float* p0 = P + (size_t)row * DMODEL;
  const float* p1 = P + ((size_t)MPAD + row) * DMODEL;
  float x0 = bf2f(xp[lane])       + p0[lane]       + p1[lane]       + bias[lane];
  float x1 = bf2f(xp[lane + 64])  + p0[lane + 64]  + p1[lane + 64]  + bias[lane + 64];
  float x2 = bf2f(xp[lane + 128]) + p0[lane + 128] + p1[lane + 128] + bias[lane + 128];
  {
    const float s  = wave_reduce_sum(x0 + x1 + x2);
    const float sq = wave_reduce_sum(x0 * x0 + x1 * x1 + x2 * x2);
    const float mu = s * (1.f / 192.f);
    const float var = sq * (1.f / 192.f) - mu * mu;
    const float rs = rsqrtf(var + 1e-5f);
    x0 = (x0 - mu) * rs * ga[lane]       + ba[lane];
    x1 = (x1 - mu) * rs * ga[lane + 64]  + ba[lane + 64];
    x2 = (x2 - mu) * rs * ga[lane + 128] + ba[lane + 128];
  }
  const float s  = wave_reduce_sum(x0 + x1 + x2);
  const float sq = wave_reduce_sum(x0 * x0 + x1 * x1 + x2 * x2);
  const float mu = s * (1.f / 192.f);
  const float var = sq * (1.f / 192.f) - mu * mu;
  const float rs = rsqrtf(var + 1e-5f);
  xp[lane]       = f2bf((x0 - mu) * rs * gb[lane]       + bb[lane]);
  xp[lane + 64]  = f2bf((x1 - mu) * rs * gb[lane + 64]  + bb[lane + 64]);
  xp[lane + 128] = f2bf((x2 - mu) * rs * gb[lane + 128] + bb[lane + 128]);
}

// ---------------- pool + head ----------------
__global__ __launch_bounds__(192) void pool_kernel(
    const ushort* __restrict__ XC, float* __restrict__ Zp)
{
  const int b = blockIdx.x, d = threadIdx.x;
  float s = 0.f;
#pragma unroll 4
  for (int l = 0; l < LLEN; ++l) s += bf2f(XC[(size_t)(b * LLEN + l) * DMODEL + d]);
  Zp[b * DMODEL + d] = s * (1.f / 197.f);
}

__global__ __launch_bounds__(256) void head_kernel(
    const float* __restrict__ Zp, const float* __restrict__ HW,
    const float* __restrict__ HB, float* __restrict__ OUTp)
{
  const int n = blockIdx.x * 256 + threadIdx.x;
  const int b = blockIdx.y;
  if (n < NCLS) {
    const float* z = Zp + b * DMODEL;
    const float* w = HW + (size_t)n * DMODEL;
    float s = HB[n];
#pragma unroll 4
    for (int d = 0; d < DMODEL; ++d) s = fmaf(z[d], w[d], s);
    OUTp[(size_t)b * NCLS + n] = s;
  }
}

// ---------------- host orchestration ----------------
extern "C" void kernel_launch(void* const* d_in, const int* in_sizes, int n_in,
                              void* d_out, int out_size, void* d_ws, size_t ws_size,
                              hipStream_t stream) {
  const float* x        = (const float*)d_in[0];
  const float* patch_w  = (const float*)d_in[1];
  const float* patch_b  = (const float*)d_in[2];
  const float* pe_ln_g  = (const float*)d_in[3];
  const float* pe_ln_b  = (const float*)d_in[4];
  const float* cls_tok  = (const float*)d_in[5];
  const float* pos_emb  = (const float*)d_in[6];
  const float* Wq = (const float*)d_in[7];
  const float* bq = (const float*)d_in[8];
  const float* Wk = (const float*)d_in[9];
  const float* bk = (const float*)d_in[10];
  const float* Wv = (const float*)d_in[11];
  const float* bv = (const float*)d_in[12];
  const float* Wo = (const float*)d_in[13];
  const float* bo = (const float*)d_in[14];
  const float* ln1_g = (const float*)d_in[15];
  const float* ln1_b = (const float*)d_in[16];
  const float* ln2_g = (const float*)d_in[17];
  const float* ln2_b = (const float*)d_in[18];
  const float* lnb_g = (const float*)d_in[19];
  const float* lnb_b = (const float*)d_in[20];
  const float* W1 = (const float*)d_in[21];
  const float* b1 = (const float*)d_in[22];
  const float* W2 = (const float*)d_in[23];
  const float* b2 = (const float*)d_in[24];
  const float* omega  = (const float*)d_in[25];
  const float* head_w = (const float*)d_in[26];
  const float* head_b = (const float*)d_in[27];
  float* out = (float*)d_out;
  char* wsb = (char*)d_ws;

  size_t off = 0;
  auto carve = [&](size_t bytes) { size_t o = off; off += (bytes + 255) & ~(size_t)255; return o; };
  ushort* xc     = (ushort*)(wsb + carve((size_t)MPAD * 192 * 2));
  ushort* qkv    = (ushort*)(wsb + carve((size_t)MPAD * 576 * 2));
  ushort* ab     = (ushort*)(wsb + carve((size_t)MPAD * 192 * 2));
  ushort* hidden = (ushort*)(wsb + carve((size_t)MPAD * 768 * 2));   // aliases im2col
  ushort* KVt    = (ushort*)(wsb + carve((size_t)192 * 80 * 256 * 2));
  float*  Pbuf   = (float*)(wsb + carve((size_t)2 * MPAD * 192 * 4)); // split-K partials
  float*  ZPb    = (float*)(wsb + carve((size_t)64 * 192 * 4));
  float*  bqkv   = (float*)(wsb + carve((size_t)12 * 576 * 4));
  ushort* Wqkv_bf = (ushort*)(wsb + carve((size_t)12 * 640 * 192 * 2));
  ushort* Wo_bf   = (ushort*)(wsb + carve((size_t)12 * 256 * 192 * 2));
  ushort* W1_bf   = (ushort*)(wsb + carve((size_t)12 * 768 * 192 * 2));
  ushort* W2_bf   = (ushort*)(wsb + carve((size_t)12 * 256 * 768 * 2));
  ushort* Wp_bf   = (ushort*)(wsb + carve((size_t)256 * 768 * 2));
  ushort* Om_bf   = (ushort*)(wsb + carve((size_t)12 * 128 * 64 * 2));
  ushort* i2c     = hidden;   // patch GEMM consumes before FF uses hidden

  // ---- pre-conversion ----
  conv_qkv<<<dim3(432, 12), 256, 0, stream>>>(Wq, Wk, Wv, bq, bk, bv, Wqkv_bf, bqkv);
  conv_pad<<<dim3(144, 12), 256, 0, stream>>>(Wo, Wo_bf, 36864, 256 * 192);
  conv_pad<<<dim3(576, 12), 256, 0, stream>>>(W1, W1_bf, 147456, 768 * 192);
  conv_pad<<<dim3(576, 12), 256, 0, stream>>>(W2, W2_bf, 147456, 256 * 768);
  conv_pad<<<dim3(576, 1), 256, 0, stream>>>(patch_w, Wp_bf, 147456, 256 * 768);
  conv_omt<<<dim3(32, 12), 256, 0, stream>>>(omega, Om_bf);

  // ---- patch embedding ----
  im2col_kernel<<<BPROWS, 256, 0, stream>>>(x, i2c);
  gemm_bf2<<<dim3(98, 3, 1), 256, 0, stream>>>(i2c, KPATCH, Wp_bf, KPATCH,
      patch_b, ab, nullptr, DMODEL, KPATCH, MODE_PLAIN);
  assemble_kernel<<<BLROWS / 4, 256, 0, stream>>>(ab, pe_ln_g, pe_ln_b,
                                                  cls_tok, pos_emb, xc);

  const int exits[3] = {3, 7, 11};
  for (int i = 0; i < NDEPTH; ++i) {
    // QKV: 128x128 tiles, N=576 -> 5 N-tiles (col-guarded), 495 blocks
    gemm_128<<<dim3(99, 5), 256, 0, stream>>>(xc, DMODEL,
        Wqkv_bf + (size_t)i * 640 * 192, DMODEL, bqkv + i * 576,
        qkv, 576, 576, DMODEL, MODE_PLAIN);
    // fused FAVOR-K + V-transpose + KV
    kv_fused<<<dim3(192, 2), 256, 0, stream>>>(qkv,
        Om_bf + (size_t)i * 8192, KVt);
    // fused FAVOR-Q + attn
    attn_fused<<<dim3(2, 192), 256, 0, stream>>>(qkv,
        Om_bf + (size_t)i * 8192, KVt, ab);
    // O-proj: split-K x2 (Kchunk 96), 594 blocks, fp32 partials
    gemm_bf2<<<dim3(99, 3, 2), 256, 0, stream>>>(ab, DMODEL,
        Wo_bf + (size_t)i * 256 * 192, DMODEL, nullptr,
        nullptr, Pbuf, DMODEL, 96, MODE_PART);
    ln1_fused<<<BLROWS / 4, 256, 0, stream>>>(xc, Pbuf, bo + i * DMODEL,
        ln1_g + i * DMODEL, ln1_b + i * DMODEL);
    // W1: 128x128 tiles, N=768 -> 6 N-tiles, 594 blocks
    gemm_128<<<dim3(99, 6), 256, 0, stream>>>(xc, DMODEL,
        W1_bf + (size_t)i * 768 * 192, DMODEL, b1 + i * FFDIM,
        hidden, FFDIM, FFDIM, DMODEL, MODE_RELU);
    // W2: split-K x2 (Kchunk 384), 594 blocks, fp32 partials
    gemm_bf2<<<dim3(99, 3, 2), 256, 0, stream>>>(hidden, FFDIM,
        W2_bf + (size_t)i * 256 * 768, FFDIM, nullptr,
        nullptr, Pbuf, DMODEL, 384, MODE_PART);
    ln2_fused<<<BLROWS / 4, 256, 0, stream>>>(xc, Pbuf, b2 + i * DMODEL,
        ln2_g + i * DMODEL, ln2_b + i * DMODEL,
        lnb_g + i * DMODEL, lnb_b + i * DMODEL);

    for (int j = 0; j < 3; ++j) {
      if (i == exits[j]) {
        pool_kernel<<<BB, 192, 0, stream>>>(xc, ZPb);
        head_kernel<<<dim3(4, BB), 256, 0, stream>>>(
            ZPb, head_w + (size_t)j * NCLS * DMODEL, head_b + (size_t)j * NCLS,
            out + (size_t)j * BB * NCLS);
      }
    }
  }
}